// Round 1
// baseline (80.534 us; speedup 1.0000x reference)
//
#include <hip/hip_runtime.h>

#define ROWS_PER_BLOCK 256
#define BLOCK_THREADS 256

__global__ __launch_bounds__(BLOCK_THREADS) void pick_rows_kernel(
    const float* __restrict__ in, float* __restrict__ out, long long nrows) {

    __shared__ float lds_in[ROWS_PER_BLOCK * 9];   // 9216 B
    __shared__ float lds_out[ROWS_PER_BLOCK * 3];  // 3072 B

    const int tid = threadIdx.x;
    const long long tileStride = (long long)gridDim.x * ROWS_PER_BLOCK;

    for (long long rowBase = (long long)blockIdx.x * ROWS_PER_BLOCK;
         rowBase < nrows; rowBase += tileStride) {

        const long long rowsLeft = nrows - rowBase;
        const int rowsHere = rowsLeft < ROWS_PER_BLOCK ? (int)rowsLeft : ROWS_PER_BLOCK;

        // ---- stage input tile into LDS (coalesced float4 when full tile) ----
        const float* src = in + rowBase * 9;
        if (rowsHere == ROWS_PER_BLOCK) {
            // 256 rows * 9 floats = 2304 floats = 576 float4 (16B-aligned:
            // rowBase is a multiple of 256 -> byte offset multiple of 9216)
            const float4* src4 = reinterpret_cast<const float4*>(src);
            #pragma unroll
            for (int i = 0; i < 576 / BLOCK_THREADS + 1; ++i) {
                int k = tid + i * BLOCK_THREADS;
                if (k < 576) {
                    float4 v = src4[k];
                    lds_in[k * 4 + 0] = v.x;
                    lds_in[k * 4 + 1] = v.y;
                    lds_in[k * 4 + 2] = v.z;
                    lds_in[k * 4 + 3] = v.w;
                }
            }
        } else {
            const int nf = rowsHere * 9;
            for (int k = tid; k < nf; k += BLOCK_THREADS) lds_in[k] = src[k];
        }
        __syncthreads();

        // ---- per-row compute ----
        if (tid < rowsHere) {
            float v[3][3];
            #pragma unroll
            for (int j = 0; j < 3; ++j)
                #pragma unroll
                for (int k = 0; k < 3; ++k)
                    v[j][k] = lds_in[tid * 9 + j * 3 + k];

            int mi[3];
            #pragma unroll
            for (int j = 0; j < 3; ++j) {
                const float a = v[j][0], b = v[j][1], c = v[j][2];
                const float m = fmaxf(a, fmaxf(b, c));
                const int ties = (int)(a == m) + (int)(b == m) + (int)(c == m);
                // first-occurrence argmax
                int am;
                if (a == m) am = 0;
                else if (b == m) am = 1;
                else am = 2;
                // CONVERT[am] = {1, 0, -1}[am] = 1 - am
                mi[j] = (ties > 1) ? 0 : (1 - am);
            }

            const int calc = (mi[1] < 0 ? -mi[1] : mi[1]) * (mi[0] + mi[1] + mi[2]);

            bool keep[3];
            #pragma unroll
            for (int j = 0; j < 3; ++j)
                keep[j] = (calc > 0 && mi[j] > 0) ||
                          (calc < 0 && mi[j] < 0) ||
                          (calc == 0 && mi[j] == 0);

            const int idx = (calc == 0) ? 1 : ((calc >= 1) ? 0 : 2);

            float vals[3];
            #pragma unroll
            for (int j = 0; j < 3; ++j)
                vals[j] = keep[j] ? v[j][idx] : 0.0f;

            // first-occurrence argmax over the 3 vals
            int win = 0;
            float best = vals[0];
            if (vals[1] > best) { best = vals[1]; win = 1; }
            if (vals[2] > best) { win = 2; }

            const bool kw = keep[win];
            #pragma unroll
            for (int k = 0; k < 3; ++k)
                lds_out[tid * 3 + k] = kw ? v[win][k] : 0.0f;
        }
        __syncthreads();

        // ---- write output tile (coalesced float4 when full tile) ----
        float* dst = out + rowBase * 3;
        if (rowsHere == ROWS_PER_BLOCK) {
            // 256 rows * 3 floats = 768 floats = 192 float4
            float4* dst4 = reinterpret_cast<float4*>(dst);
            if (tid < 192) {
                float4 o;
                o.x = lds_out[tid * 4 + 0];
                o.y = lds_out[tid * 4 + 1];
                o.z = lds_out[tid * 4 + 2];
                o.w = lds_out[tid * 4 + 3];
                dst4[tid] = o;
            }
        } else {
            const int nf = rowsHere * 3;
            for (int k = tid; k < nf; k += BLOCK_THREADS) dst[k] = lds_out[k];
        }
        __syncthreads();
    }
}

extern "C" void kernel_launch(void* const* d_in, const int* in_sizes, int n_in,
                              void* d_out, int out_size, void* d_ws, size_t ws_size,
                              hipStream_t stream) {
    const float* in = (const float*)d_in[0];
    float* out = (float*)d_out;
    const long long nrows = (long long)in_sizes[0] / 9;

    const long long tiles = (nrows + ROWS_PER_BLOCK - 1) / ROWS_PER_BLOCK;
    int grid = (int)(tiles < 2048 ? tiles : 2048);
    pick_rows_kernel<<<grid, BLOCK_THREADS, 0, stream>>>(in, out, nrows);
}

// Round 2
// 80.194 us; speedup vs baseline: 1.0042x; 1.0042x over previous
//
#include <hip/hip_runtime.h>

// Per-row semantics (row = 9 floats = x[3][3]):
//   mi[j]  = ties ? 0 : (1 - argmax(x[j]))        in {1,0,-1}
//   calc   = |mi[1]| * (mi[0]+mi[1]+mi[2])
//   keep[j]= sign(mi[j]) == sign(calc)  (0 matches 0)
//   idx    = calc==0 ? 1 : (calc>=1 ? 0 : 2)
//   vals[j]= keep[j] ? x[j][idx] : 0
//   win    = first-occurrence argmax(vals)
//   out    = keep[win] ? x[win][:] : 0,0,0

__device__ __forceinline__ void compute_row(
    float v00, float v01, float v02,
    float v10, float v11, float v12,
    float v20, float v21, float v22,
    float& o0, float& o1, float& o2) {

    float v[3][3] = {{v00, v01, v02}, {v10, v11, v12}, {v20, v21, v22}};

    int mi[3];
#pragma unroll
    for (int j = 0; j < 3; ++j) {
        const float a = v[j][0], b = v[j][1], c = v[j][2];
        const float m = fmaxf(a, fmaxf(b, c));
        const int ties = (int)(a == m) + (int)(b == m) + (int)(c == m);
        int am;
        if (a == m) am = 0;
        else if (b == m) am = 1;
        else am = 2;
        mi[j] = (ties > 1) ? 0 : (1 - am);
    }

    const int calc = (mi[1] < 0 ? -mi[1] : mi[1]) * (mi[0] + mi[1] + mi[2]);

    bool keep[3];
#pragma unroll
    for (int j = 0; j < 3; ++j)
        keep[j] = (calc > 0 && mi[j] > 0) ||
                  (calc < 0 && mi[j] < 0) ||
                  (calc == 0 && mi[j] == 0);

    const int idx = (calc == 0) ? 1 : ((calc >= 1) ? 0 : 2);

    float vals[3];
#pragma unroll
    for (int j = 0; j < 3; ++j) {
        // constant-index select of v[j][idx]
        const float vj = (idx == 0) ? v[j][0] : ((idx == 2) ? v[j][2] : v[j][1]);
        vals[j] = keep[j] ? vj : 0.0f;
    }

    // first-occurrence argmax over vals, via constant-index selects
    const bool w1 = vals[1] > vals[0];
    const float b01 = w1 ? vals[1] : vals[0];
    const bool w2 = vals[2] > b01;

    const bool keepw = w2 ? keep[2] : (w1 ? keep[1] : keep[0]);

    const float r0 = w2 ? v[2][0] : (w1 ? v[1][0] : v[0][0]);
    const float r1 = w2 ? v[2][1] : (w1 ? v[1][1] : v[0][1]);
    const float r2 = w2 ? v[2][2] : (w1 ? v[1][2] : v[0][2]);

    o0 = keepw ? r0 : 0.0f;
    o1 = keepw ? r1 : 0.0f;
    o2 = keepw ? r2 : 0.0f;
}

__global__ __launch_bounds__(256) void pick_rows_kernel(
    const float* __restrict__ in, float* __restrict__ out, long long nrows) {

    const long long t = (long long)blockIdx.x * blockDim.x + threadIdx.x;
    const long long r0 = t * 4;
    if (r0 >= nrows) return;

    if (r0 + 4 <= nrows) {
        // 4 rows = 36 floats = 9 float4, 16B-aligned (byte offset 144*t)
        const float4* p4 = reinterpret_cast<const float4*>(in + r0 * 9);
        float4 f[9];
#pragma unroll
        for (int i = 0; i < 9; ++i) f[i] = p4[i];

        float x[36];
#pragma unroll
        for (int i = 0; i < 9; ++i) {
            x[i * 4 + 0] = f[i].x;
            x[i * 4 + 1] = f[i].y;
            x[i * 4 + 2] = f[i].z;
            x[i * 4 + 3] = f[i].w;
        }

        float o[12];
#pragma unroll
        for (int j = 0; j < 4; ++j) {
            compute_row(x[j * 9 + 0], x[j * 9 + 1], x[j * 9 + 2],
                        x[j * 9 + 3], x[j * 9 + 4], x[j * 9 + 5],
                        x[j * 9 + 6], x[j * 9 + 7], x[j * 9 + 8],
                        o[j * 3 + 0], o[j * 3 + 1], o[j * 3 + 2]);
        }

        // 12 floats = 3 float4, 16B-aligned (byte offset 48*t)
        float4* q4 = reinterpret_cast<float4*>(out + r0 * 3);
        float4 q;
        q.x = o[0];  q.y = o[1];  q.z = o[2];  q.w = o[3];
        q4[0] = q;
        q.x = o[4];  q.y = o[5];  q.z = o[6];  q.w = o[7];
        q4[1] = q;
        q.x = o[8];  q.y = o[9];  q.z = o[10]; q.w = o[11];
        q4[2] = q;
    } else {
        // scalar tail (rows not a multiple of 4)
        for (long long r = r0; r < nrows; ++r) {
            const float* p = in + r * 9;
            float o0, o1, o2;
            compute_row(p[0], p[1], p[2], p[3], p[4], p[5], p[6], p[7], p[8],
                        o0, o1, o2);
            out[r * 3 + 0] = o0;
            out[r * 3 + 1] = o1;
            out[r * 3 + 2] = o2;
        }
    }
}

extern "C" void kernel_launch(void* const* d_in, const int* in_sizes, int n_in,
                              void* d_out, int out_size, void* d_ws, size_t ws_size,
                              hipStream_t stream) {
    const float* in = (const float*)d_in[0];
    float* out = (float*)d_out;
    const long long nrows = (long long)in_sizes[0] / 9;

    const long long nthreads = (nrows + 3) / 4;
    const int block = 256;
    const long long nblocks = (nthreads + block - 1) / block;
    pick_rows_kernel<<<(int)nblocks, block, 0, stream>>>(in, out, nrows);
}